// Round 11
// baseline (551.068 us; speedup 1.0000x reference)
//
#include <hip/hip_runtime.h>

// PCLSTM B=512,C=128,H=128,T=512 — round 11: r10 + spread-xzg + service waves.
// 256 wgs x 768 thr (12 waves, 1 wg/CU). Waves 0-7 (compute): i8 h-GEMM
// (8 MFMA/step), quadrant-packed EW, PLUS a 1-chunk slice of the bf16 x-part
// octet GEMM on octet-phases 1-4 (4 MFMA/step, acc held in regs) — no spikes.
// Waves 8-11 (service): x staging + output flush only. One raw barrier/step.
// s_setprio(1) around the h-MFMA block.

#define BB 512
#define CC 128
#define HH 128
#define TT 512
#define MB 2
#define XSP 168   // xs row stride (u16)
#define XZP 516   // xz row stride (f32), rows = 2*dt+b
#define OPH 33    // hbuf inner stride (u16)

typedef __attribute__((ext_vector_type(8))) short short8;
typedef __attribute__((ext_vector_type(4))) float f32x4;
typedef __attribute__((ext_vector_type(4))) int v4i;

#define SW 2032.0f
#define SH 127.0f
#define INV_SHW (1.0f / (127.0f * 2032.0f))

__device__ inline unsigned short f2bf(float f) {
    unsigned u = __builtin_bit_cast(unsigned, f);
    u = u + 0x7FFFu + ((u >> 16) & 1u);   // RNE
    return (unsigned short)(u >> 16);
}
__device__ inline float bf2f(unsigned short s) {
    unsigned u = ((unsigned)s) << 16;
    return __builtin_bit_cast(float, u);
}

#define BAR() asm volatile("s_waitcnt lgkmcnt(0)\n\ts_barrier" ::: "memory")

__global__ __launch_bounds__(768, 3) void pclstm_kernel(
    const float* __restrict__ x,
    const float* __restrict__ Wf, const float* __restrict__ bfp,
    const float* __restrict__ Wi, const float* __restrict__ bip,
    const float* __restrict__ Wu, const float* __restrict__ bup,
    const float* __restrict__ Wo, const float* __restrict__ bop,
    float* __restrict__ out)
{
    __shared__ unsigned short xs[64][XSP];          // x bf16: row = 2*(t&31)+b
    __shared__ signed char hs8[2][2][192];          // h i8, double-buffered [p][b][n]
    __shared__ float xz[2][16][XZP];                // x-preacts f32: [buf][2dt+b][un*4+g]
    __shared__ float ew[8][16][12];                 // per-wave act exchange
    __shared__ unsigned short hbuf[2][2][HH][OPH];  // h out bf16, 32-step chunks

    const int tid  = threadIdx.x;
    const int lane = tid & 63;
    const int wid  = tid >> 6;            // 0..11
    const int bg0  = blockIdx.x * MB;
    const int l15  = lane & 15;
    const int q    = lane >> 4;           // quadrant
    const int koff = q << 3;              // bf16 K=32 frag k-offset
    const int kq   = q << 4;              // i8 K=64 frag k-offset
    const int un   = (wid & 7) * 16 + l15;// compute: owned unit
    const int cq4  = (un << 2) + q;
    float* outH = out;
    float* outC = out + (size_t)BB * HH * TT;

    // act constants: quadrant 2 is tanh (=2*sigmoid(2z)-1), others sigmoid
    const float esc = (q == 2) ? -2.885390082f : -1.442695041f;
    const float ym  = (q == 2) ? 2.0f : 1.0f;
    const float yk  = (q == 2) ? -1.0f : 0.0f;

    // ---------------- compute-wave state (wid 0-7) ----------------
    short8 wx[4][4];          // bf16 x-part weights
    v4i wh[4][2];             // i8 h-part weights
    float bias[4] = {0, 0, 0, 0};
    f32x4 a2[4];              // spread-xzg accumulators
    float cst = 0.0f;

    // ---------------- service-wave state (wid 8-11) ----------------
    const int sid = ((wid - 8) << 6) + lane;     // 0..255
    const int scc = sid >> 1, sh2 = sid & 1;     // staging: channel, half
    const int fbx = sid >> 7, fnx = sid & 127;   // flush: batch, unit
    f32x4 stg[2][2];

    if (wid < 8) {
        const float* Wg[4] = {Wf, Wi, Wu, Wo};
        const float* Bg[4] = {bfp, bip, bup, bop};
        #pragma unroll
        for (int g = 0; g < 4; ++g) {
            bias[g] = Bg[g][un];
            #pragma unroll
            for (int kt = 0; kt < 4; ++kt) {
                short8 v;
                #pragma unroll
                for (int i = 0; i < 8; ++i)
                    v[i] = (short)f2bf(Wg[g][(kt * 32 + koff + i) * HH + un]);
                wx[g][kt] = v;
            }
            #pragma unroll
            for (int kf = 0; kf < 2; ++kf) {
                v4i v;
                #pragma unroll
                for (int d = 0; d < 4; ++d) {
                    unsigned pw = 0;
                    #pragma unroll
                    for (int e = 0; e < 4; ++e) {
                        int qv = (int)__builtin_rintf(
                            Wg[g][(128 + kf * 64 + kq + d * 4 + e) * HH + un] * SW);
                        pw |= ((unsigned)(qv & 255)) << (8 * e);
                    }
                    v[d] = (int)pw;
                }
                wh[g][kf] = v;
            }
        }
    } else {
        // prologue staging: window [0,16), 2 quarters per thread per row
        #pragma unroll
        for (int pr = 0; pr < 2; ++pr) {
            const int qq = sh2 * 2 + pr;
            const float* xp = x + ((size_t)bg0 * CC + scc) * TT + qq * 4;
            f32x4 v0 = *(const f32x4*)xp;
            f32x4 v1 = *(const f32x4*)(xp + (size_t)CC * TT);
            #pragma unroll
            for (int j = 0; j < 4; ++j) {
                xs[2 * (qq * 4 + j) + 0][scc] = f2bf(v0[j]);
                xs[2 * (qq * 4 + j) + 1][scc] = f2bf(v1[j]);
            }
        }
    }
    for (int i = tid; i < 2 * 2 * 192; i += 768)
        ((signed char*)hs8)[i] = 0;
    __syncthreads();

    // prologue: full octet GEMM for TB=0 (compute waves)
    if (wid < 8) {
        #pragma unroll
        for (int g = 0; g < 4; ++g)
            a2[g] = (f32x4){bias[g], bias[g], bias[g], bias[g]};
        #pragma unroll
        for (int kt = 0; kt < 4; ++kt) {
            const int s = kt * 0 + (l15 >> 1);   // TB=0
            short8 a = *(const short8*)&xs[2 * s + (lane & 1)][kt * 32 + koff];
            #pragma unroll
            for (int g = 0; g < 4; ++g)
                a2[g] = __builtin_amdgcn_mfma_f32_16x16x32_bf16(a, wx[g][kt], a2[g], 0, 0, 0);
        }
        const int r0 = q << 2;
        #pragma unroll
        for (int r = 0; r < 4; ++r) {
            f32x4 vv = {a2[0][r], a2[1][r], a2[2][r], a2[3][r]};
            *(f32x4*)&xz[0][r0 + r][un << 2] = vv;
        }
    }
    __syncthreads();

    float nxa = 0.0f, nxb = 0.0f;
    if (wid < 8) {
        nxa = xz[0][0][cq4];
        nxb = xz[0][1][cq4];
    }

    for (int t = 0; t < TT; ++t) {
        const int p = t & 1;
        if (wid < 8) {
            // ---- h-part MFMA: i8, i32 exact ----
            v4i a0 = *(const v4i*)&hs8[p][lane & 1][kq];
            v4i a1 = *(const v4i*)&hs8[p][lane & 1][64 + kq];
            float xa = nxa, xb = nxb;
            {   // prefetch next step's xz
                const int t1 = t + 1;
                const int buf1 = (t1 >> 3) & 1, dt1 = t1 & 7;
                nxa = xz[buf1][2 * dt1 + 0][cq4];
                nxb = xz[buf1][2 * dt1 + 1][cq4];
            }
            __builtin_amdgcn_s_setprio(1);
            v4i zi[4];
            #pragma unroll
            for (int g = 0; g < 4; ++g) {
                v4i ac = {0, 0, 0, 0};
                ac = __builtin_amdgcn_mfma_i32_16x16x64_i8(a0, wh[g][0], ac, 0, 0, 0);
                zi[g] = __builtin_amdgcn_mfma_i32_16x16x64_i8(a1, wh[g][1], ac, 0, 0, 0);
            }
            __builtin_amdgcn_s_setprio(0);

            // ---- spread xzg: one k-chunk on octet phases 1..4 ----
            {
                const int ph = t & 7;
                const int TB = (t & ~7) + 8;
                if (ph >= 1 && ph <= 4 && TB < TT) {
                    const int kt = ph - 1;
                    const int s = (TB + (l15 >> 1)) & 31;
                    short8 a = *(const short8*)&xs[2 * s + (lane & 1)][kt * 32 + koff];
                    if (kt == 0) {
                        #pragma unroll
                        for (int g = 0; g < 4; ++g)
                            a2[g] = (f32x4){bias[g], bias[g], bias[g], bias[g]};
                    }
                    #pragma unroll
                    for (int g = 0; g < 4; ++g)
                        a2[g] = __builtin_amdgcn_mfma_f32_16x16x32_bf16(a, wx[g][kt], a2[g], 0, 0, 0);
                    if (kt == 3) {
                        const int bufw = (TB >> 3) & 1;
                        const int r0 = q << 2;
                        #pragma unroll
                        for (int r = 0; r < 4; ++r) {
                            f32x4 vv = {a2[0][r], a2[1][r], a2[2][r], a2[3][r]};
                            *(f32x4*)&xz[bufw][r0 + r][un << 2] = vv;
                        }
                    }
                }
            }

            // ---- EW: quadrant q computes gate q's act (all 64 lanes) ----
            int zs0 = (q & 2) ? ((q & 1) ? zi[3][0] : zi[2][0])
                              : ((q & 1) ? zi[1][0] : zi[0][0]);
            int zs1 = (q & 2) ? ((q & 1) ? zi[3][1] : zi[2][1])
                              : ((q & 1) ? zi[1][1] : zi[0][1]);
            float z0 = (float)zs0 * INV_SHW + xa;
            float z1 = (float)zs1 * INV_SHW + xb;
            float ya = ym * __builtin_amdgcn_rcpf(
                           1.0f + __builtin_amdgcn_exp2f(esc * z0)) + yk;
            float yb = ym * __builtin_amdgcn_rcpf(
                           1.0f + __builtin_amdgcn_exp2f(esc * z1)) + yk;
            ew[wid][l15][q]     = ya;
            ew[wid][l15][4 + q] = yb;
            // handlers: lanes 0-31, (b = lane>>4, unit = un)
            if (lane < 32) {
                const int hbx = lane >> 4;
                f32x4 g4 = *(const f32x4*)&ew[wid][l15][hbx * 4];   // f,i,u,o
                cst = cst * g4[0] + g4[1] * g4[2];
                float th = 2.0f * __builtin_amdgcn_rcpf(
                               1.0f + __builtin_amdgcn_exp2f(-2.885390082f * cst)) - 1.0f;
                float h = g4[3] * th;
                hs8[p ^ 1][hbx][un] = (signed char)(int)__builtin_rintf(h * SH);
                hbuf[(t >> 5) & 1][hbx][un][t & 31] = f2bf(h);
            }
        } else {
            const int tm = t & 15;
            if (tm == 0) {
                if (t + 16 < TT) {
                    #pragma unroll
                    for (int pr = 0; pr < 2; ++pr) {
                        const int qq = sh2 * 2 + pr;
                        const float* xp = x + ((size_t)bg0 * CC + scc) * TT
                                          + (t + 16) + qq * 4;
                        stg[pr][0] = *(const f32x4*)xp;
                        stg[pr][1] = *(const f32x4*)(xp + (size_t)CC * TT);
                    }
                }
            } else if (tm == 8) {
                if (t + 8 < TT) {
                    #pragma unroll
                    for (int pr = 0; pr < 2; ++pr) {
                        const int qq = sh2 * 2 + pr;
                        #pragma unroll
                        for (int j = 0; j < 4; ++j) {
                            int sl = (t + 8 + qq * 4 + j) & 31;
                            xs[2 * sl + 0][scc] = f2bf(stg[pr][0][j]);
                            xs[2 * sl + 1][scc] = f2bf(stg[pr][1][j]);
                        }
                    }
                }
            }
            if ((t & 31) == 12 && t >= 32) {
                const int ocp = (t >> 5) - 1;
                const unsigned short* hp = &hbuf[ocp & 1][fbx][fnx][0];
                float* op = outH + ((size_t)(bg0 + fbx) * HH + fnx) * TT + ocp * 32;
                #pragma unroll
                for (int k = 0; k < 8; ++k) {
                    f32x4 o;
                    #pragma unroll
                    for (int j = 0; j < 4; ++j)
                        o[j] = bf2f(hp[k * 4 + j]);
                    *(f32x4*)(op + k * 4) = o;
                }
            }
        }
        BAR();
    }

    // ---- epilogue: final chunk (service) + c_final (compute handlers) ----
    if (wid >= 8) {
        const unsigned short* hp = &hbuf[1][fbx][fnx][0];
        float* op = outH + ((size_t)(bg0 + fbx) * HH + fnx) * TT + 480;
        #pragma unroll
        for (int k = 0; k < 8; ++k) {
            f32x4 o;
            #pragma unroll
            for (int j = 0; j < 4; ++j)
                o[j] = bf2f(hp[k * 4 + j]);
            *(f32x4*)(op + k * 4) = o;
        }
    }
    if (wid < 8 && lane < 32)
        outC[(size_t)(bg0 + (lane >> 4)) * HH + un] = cst;
}

extern "C" void kernel_launch(void* const* d_in, const int* in_sizes, int n_in,
                              void* d_out, int out_size, void* d_ws, size_t ws_size,
                              hipStream_t stream) {
    const float* x  = (const float*)d_in[0];
    const float* Wf = (const float*)d_in[1];
    const float* bf = (const float*)d_in[2];
    const float* Wi = (const float*)d_in[3];
    const float* bi = (const float*)d_in[4];
    const float* Wu = (const float*)d_in[5];
    const float* bu = (const float*)d_in[6];
    const float* Wo = (const float*)d_in[7];
    const float* bo = (const float*)d_in[8];
    float* out = (float*)d_out;

    dim3 grid(BB / MB);   // 256 workgroups, 1 per CU
    dim3 block(768);      // 12 waves: 8 compute + 4 service
    pclstm_kernel<<<grid, block, 0, stream>>>(x, Wf, bf, Wi, bi, Wu, bu, Wo, bo, out);
}

// Round 13
// 311.164 us; speedup vs baseline: 1.7710x; 1.7710x over previous
//
#include <hip/hip_runtime.h>

// PCLSTM B=512,C=128,H=128,T=512 — round 13: r12 with safe __shfl_xor exchange.
// 256 wgs x 512 thr (8 waves, 1 wg/CU). Wave w owns ALL 4 gates of units
// [16w,16w+16). i8 h-GEMM (8 MFMA/wave/step, i32 exact acc). bf16 x-part
// octet GEMM every 8 steps. EW: quadrant q computes a GATE PAIR for batch
// b=q>>1 (even q -> (f,i), odd q -> (u,o); odd slot always sigmoid);
// exchange across lane^16 via __shfl_xor (single conflict-free DS op);
// all 64 lanes run the c/h chain; quadrants 0,2 commit. No ew LDS buffer.

#define BB 512
#define CC 128
#define HH 128
#define TT 512
#define MB 2
#define XSP 168   // xs row stride (u16)
#define XZP 516   // xz row stride (f32), rows = 2*dt+b
#define OPH 33    // hbuf inner stride (u16)

typedef __attribute__((ext_vector_type(8))) short short8;
typedef __attribute__((ext_vector_type(4))) float f32x4;
typedef __attribute__((ext_vector_type(2))) float f32x2;
typedef __attribute__((ext_vector_type(4))) int v4i;

#define SW 2032.0f
#define SH 127.0f
#define INV_SHW (1.0f / (127.0f * 2032.0f))

__device__ inline unsigned short f2bf(float f) {
    unsigned u = __builtin_bit_cast(unsigned, f);
    u = u + 0x7FFFu + ((u >> 16) & 1u);   // RNE
    return (unsigned short)(u >> 16);
}
__device__ inline float bf2f(unsigned short s) {
    unsigned u = ((unsigned)s) << 16;
    return __builtin_bit_cast(float, u);
}

#define BAR() asm volatile("s_waitcnt lgkmcnt(0)\n\ts_barrier" ::: "memory")

__global__ __launch_bounds__(512, 2) void pclstm_kernel(
    const float* __restrict__ x,
    const float* __restrict__ Wf, const float* __restrict__ bfp,
    const float* __restrict__ Wi, const float* __restrict__ bip,
    const float* __restrict__ Wu, const float* __restrict__ bup,
    const float* __restrict__ Wo, const float* __restrict__ bop,
    float* __restrict__ out)
{
    __shared__ unsigned short xs[64][XSP];          // x bf16: row = 2*(t&31)+b
    __shared__ signed char hs8[2][2][192];          // h i8, double-buffered [p][b][n]
    __shared__ float xz[2][16][XZP];                // x-preacts f32: [buf][2dt+b][un*4+g]
    __shared__ unsigned short hbuf[2][2][HH][OPH];  // h out bf16, 32-step chunks

    const int tid  = threadIdx.x;
    const int lane = tid & 63;
    const int wid  = tid >> 6;            // 0..7
    const int bg0  = blockIdx.x * MB;
    const int l15  = lane & 15;
    const int q    = lane >> 4;           // quadrant
    const int qe   = q & 1;               // 0: gates (f,i); 1: gates (u,o)
    const int rb   = q >> 1;              // batch row handled by this lane
    const int b4   = lane & 16;           // nonzero for quadrants 1,3
    const int koff = q << 3;              // bf16 K=32 frag k-offset
    const int kq   = q << 4;              // i8 K=64 frag k-offset
    const int un   = wid * 16 + l15;      // owned unit
    const int cqe  = (un << 2) + (qe << 1);  // xz col base for own gate pair

    // act constants for the EVEN slot: qe==1 -> tanh (u), else sigmoid (f)
    const float esc_e = qe ? -2.885390082f : -1.442695041f;
    const float ym_e  = qe ? 2.0f : 1.0f;
    const float yk_e  = qe ? -1.0f : 0.0f;

    // ---- weights: wx bf16 (x-part), wh i8 (h-part), all 4 gates of unit un ----
    const float* Wg[4] = {Wf, Wi, Wu, Wo};
    const float* Bg[4] = {bfp, bip, bup, bop};
    short8 wx[4][4];
    v4i wh[4][2];
    float bias[4];
    #pragma unroll
    for (int g = 0; g < 4; ++g) {
        bias[g] = Bg[g][un];
        #pragma unroll
        for (int kt = 0; kt < 4; ++kt) {
            short8 v;
            #pragma unroll
            for (int i = 0; i < 8; ++i)
                v[i] = (short)f2bf(Wg[g][(kt * 32 + koff + i) * HH + un]);
            wx[g][kt] = v;
        }
        #pragma unroll
        for (int kf = 0; kf < 2; ++kf) {
            v4i v;
            #pragma unroll
            for (int d = 0; d < 4; ++d) {
                unsigned pw = 0;
                #pragma unroll
                for (int e = 0; e < 4; ++e) {
                    int qv = (int)__builtin_rintf(
                        Wg[g][(128 + kf * 64 + kq + d * 4 + e) * HH + un] * SW);
                    pw |= ((unsigned)(qv & 255)) << (8 * e);
                }
                v[d] = (int)pw;
            }
            wh[g][kf] = v;
        }
    }

    for (int i = tid; i < 2 * 2 * 192; i += 512)
        ((signed char*)hs8)[i] = 0;

    // ---- stage x chunk [0,16) ----
    {
        int cc = (tid >> 2) & 127, sq0 = tid & 3;
        const float* xp = x + ((size_t)bg0 * CC + cc) * TT + sq0 * 4;
        f32x4 v0 = *(const f32x4*)xp;
        f32x4 v1 = *(const f32x4*)(xp + (size_t)CC * TT);
        #pragma unroll
        for (int j = 0; j < 4; ++j) {
            xs[2 * (sq0 * 4 + j) + 0][cc] = f2bf(v0[j]);
            xs[2 * (sq0 * 4 + j) + 1][cc] = f2bf(v1[j]);
        }
    }
    __syncthreads();

    // x-part octet GEMM (bf16): m=16 tile = (8 steps x 2 batch), K=128.
    auto xzg = [&](int TB) {
        const int buf = (TB >> 3) & 1;
        f32x4 a2[4];
        #pragma unroll
        for (int g = 0; g < 4; ++g)
            a2[g] = (f32x4){bias[g], bias[g], bias[g], bias[g]};
        #pragma unroll
        for (int kt = 0; kt < 4; ++kt) {
            const int s = (TB + (l15 >> 1)) & 31;
            short8 a = *(const short8*)&xs[2 * s + (lane & 1)][kt * 32 + koff];
            #pragma unroll
            for (int g = 0; g < 4; ++g)
                a2[g] = __builtin_amdgcn_mfma_f32_16x16x32_bf16(a, wx[g][kt], a2[g], 0, 0, 0);
        }
        const int row0 = q << 2;              // D row = 2*dt + b
        #pragma unroll
        for (int r = 0; r < 4; ++r) {
            f32x4 vv = {a2[0][r], a2[1][r], a2[2][r], a2[3][r]};
            *(f32x4*)&xz[buf][row0 + r][un << 2] = vv;
        }
    };

    xzg(0);
    __syncthreads();

    // xz prefetch for t=0: own gate pair (2 f32) for own batch row
    f32x2 nx = *(const f32x2*)&xz[0][rb][cqe];

    float cst = 0.0f;                     // c-state: all lanes, b = rb
    f32x4 stg0 = {0, 0, 0, 0}, stg1 = {0, 0, 0, 0};
    float* outH = out;
    float* outC = out + (size_t)BB * HH * TT;
    const int scc = (tid >> 2) & 127, sq = tid & 3;
    const int fb = tid >> 8, fn = (tid >> 1) & 127, fh = tid & 1;

    for (int t = 0; t < TT; ++t) {
        const int p = t & 1;
        // ---- h-part MFMA: i8, i32 exact accumulation ----
        v4i a0 = *(const v4i*)&hs8[p][lane & 1][kq];
        v4i a1 = *(const v4i*)&hs8[p][lane & 1][64 + kq];
        v4i zi[4];
        #pragma unroll
        for (int g = 0; g < 4; ++g) {
            v4i ac = {0, 0, 0, 0};
            ac = __builtin_amdgcn_mfma_i32_16x16x64_i8(a0, wh[g][0], ac, 0, 0, 0);
            zi[g] = __builtin_amdgcn_mfma_i32_16x16x64_i8(a1, wh[g][1], ac, 0, 0, 0);
        }

        // ---- service (uniform branches) ----
        const int tm = t & 15;
        if (tm == 0) {
            if (t + 16 < TT) {
                const float* xp = x + ((size_t)bg0 * CC + scc) * TT + (t + 16) + sq * 4;
                stg0 = *(const f32x4*)xp;
                stg1 = *(const f32x4*)(xp + (size_t)CC * TT);
            }
        } else if (tm == 8) {
            if (t + 8 < TT) {
                #pragma unroll
                for (int j = 0; j < 4; ++j) {
                    int sl = (t + 8 + sq * 4 + j) & 31;
                    xs[2 * sl + 0][scc] = f2bf(stg0[j]);
                    xs[2 * sl + 1][scc] = f2bf(stg1[j]);
                }
            }
        }
        if ((t & 7) == 1 && t + 7 < TT)
            xzg(t + 7);
        if ((t & 31) == 12 && t >= 32) {
            const int ocp = (t >> 5) - 1;
            const unsigned short* hb = &hbuf[ocp & 1][fb][fn][fh * 16];
            float* op = outH + ((size_t)(bg0 + fb) * HH + fn) * TT + ocp * 32 + fh * 16;
            f32x4 o[4];
            #pragma unroll
            for (int j = 0; j < 16; ++j)
                o[j >> 2][j & 3] = bf2f(hb[j]);
            #pragma unroll
            for (int qq = 0; qq < 4; ++qq)
                *(f32x4*)(op + 4 * qq) = o[qq];
        }

        // ---- EW: quadrant gate-pairs + shfl_xor exchange ----
        {
            f32x2 xa = nx;
            {   // prefetch next step's xz
                const int t1 = t + 1;
                const int buf1 = (t1 >> 3) & 1, dt1 = t1 & 7;
                nx = *(const f32x2*)&xz[buf1][2 * dt1 + rb][cqe];
            }
            // own-batch z for own gate pair (quadrant-identical D regs 0,1)
            int zf = rb ? zi[0][1] : zi[0][0];
            int zig = rb ? zi[1][1] : zi[1][0];
            int zu = rb ? zi[2][1] : zi[2][0];
            int zo = rb ? zi[3][1] : zi[3][0];
            int z_e = qe ? zu : zf;
            int z_o = qe ? zo : zig;
            float ze = (float)z_e * INV_SHW + xa.x;
            float zod = (float)z_o * INV_SHW + xa.y;
            // even slot: sigmoid(f) or tanh(u); odd slot: always sigmoid (i,o)
            float act_e = ym_e * __builtin_amdgcn_rcpf(
                              1.0f + __builtin_amdgcn_exp2f(esc_e * ze)) + yk_e;
            float act_o = __builtin_amdgcn_rcpf(
                              1.0f + __builtin_amdgcn_exp2f(-1.442695041f * zod));
            // exchange with lane^16 (other gate pair, same batch)
            float cr_e = __shfl_xor(act_e, 16, 64);
            float cr_o = __shfl_xor(act_o, 16, 64);
            float fg = qe ? cr_e : act_e;
            float ig = qe ? cr_o : act_o;
            float ug = qe ? act_e : cr_e;
            float og = qe ? act_o : cr_o;
            cst = cst * fg + ig * ug;
            float th = 2.0f * __builtin_amdgcn_rcpf(
                           1.0f + __builtin_amdgcn_exp2f(-2.885390082f * cst)) - 1.0f;
            float h = og * th;
            if (!b4) {   // quadrants 0,2 commit (b = rb)
                hs8[p ^ 1][rb][un] = (signed char)(int)__builtin_rintf(h * SH);
                hbuf[(t >> 5) & 1][rb][un][t & 31] = f2bf(h);
            }
        }
        BAR();
    }

    // ---- final flush: chunk 15 ----
    {
        const unsigned short* hb = &hbuf[1][fb][fn][fh * 16];
        float* op = outH + ((size_t)(bg0 + fb) * HH + fn) * TT + 480 + fh * 16;
        f32x4 o[4];
        #pragma unroll
        for (int j = 0; j < 16; ++j)
            o[j >> 2][j & 3] = bf2f(hb[j]);
        #pragma unroll
        for (int qq = 0; qq < 4; ++qq)
            *(f32x4*)(op + 4 * qq) = o[qq];
    }
    if (!b4)
        outC[(size_t)(bg0 + rb) * HH + un] = cst;
}

extern "C" void kernel_launch(void* const* d_in, const int* in_sizes, int n_in,
                              void* d_out, int out_size, void* d_ws, size_t ws_size,
                              hipStream_t stream) {
    const float* x  = (const float*)d_in[0];
    const float* Wf = (const float*)d_in[1];
    const float* bf = (const float*)d_in[2];
    const float* Wi = (const float*)d_in[3];
    const float* bi = (const float*)d_in[4];
    const float* Wu = (const float*)d_in[5];
    const float* bu = (const float*)d_in[6];
    const float* Wo = (const float*)d_in[7];
    const float* bo = (const float*)d_in[8];
    float* out = (float*)d_out;

    dim3 grid(BB / MB);   // 256 workgroups, 1 per CU
    dim3 block(512);      // 8 waves
    pclstm_kernel<<<grid, block, 0, stream>>>(x, Wf, bf, Wi, bi, Wu, bu, Wo, bo, out);
}